// Round 1
// baseline (927.979 us; speedup 1.0000x reference)
//
#include <hip/hip_runtime.h>
#include <cstddef>

// Problem constants (B=2,H=16 -> BH=32)
#define BH    32
#define NSEQ  4096
#define DHEAD 64
#define MFEAT 256
#define CHUNK 128
#define NCH   32    // NSEQ/CHUNK

typedef unsigned int uint_t;

// ---------- helpers ----------
__device__ __forceinline__ float h2f_lo(uint_t u) {
  union { uint_t u; _Float16 h[2]; } c; c.u = u; return (float)c.h[0];
}
__device__ __forceinline__ float h2f_hi(uint_t u) {
  union { uint_t u; _Float16 h[2]; } c; c.u = u; return (float)c.h[1];
}
__device__ __forceinline__ uint_t pack2h(float a, float b) {
  union { uint_t u; _Float16 h[2]; } c; c.h[0] = (_Float16)a; c.h[1] = (_Float16)b; return c.u;
}
// order-preserving float<->uint encoding for atomicMax on floats (incl. negatives)
__device__ __forceinline__ uint_t enc_f(float x) {
  uint_t u = __float_as_uint(x);
  return (u & 0x80000000u) ? ~u : (u | 0x80000000u);
}
__device__ __forceinline__ float dec_f(uint_t u) {
  u = (u & 0x80000000u) ? (u ^ 0x80000000u) : ~u;
  return __uint_as_float(u);
}

__global__ void k_init(uint_t* kmax) { *kmax = enc_f(-__builtin_inff()); }

// ---------- projection kernels: proj = (x*scale) @ omega^T ; lp = proj - 0.5*|x*scale|^2
// MODE 0: phi_q (per-row max, exp, store fp16)
// MODE 1: k global max only (atomicMax)
// MODE 2: phi_k final (uses global max, exp, store fp16)
template <int MODE>
__global__ __launch_bounds__(256) void k_proj(
    const float* __restrict__ x, const float* __restrict__ omega,
    _Float16* __restrict__ phiOut, uint_t* __restrict__ kmax)
{
  __shared__ float xs[64][68];     // 64 rows of x (scaled)
  __shared__ float wsm[256][68];   // omega [m][d]; aliased as store staging later
  __shared__ float redbuf[4];

  const int tid = threadIdx.x;
  const int ti = tid >> 4, tj = tid & 15;
  const size_t rowbase = (size_t)blockIdx.x * 64;
  const float scale = 0.35355339059327373f;  // 64^-0.25

  for (int l = tid * 4; l < 16384; l += 1024) {
    float4 o = *(const float4*)(omega + l);
    *(float4*)&wsm[l >> 6][l & 63] = o;
  }
  for (int l = tid * 4; l < 4096; l += 1024) {
    float4 vv = *(const float4*)(x + rowbase * 64 + l);
    vv.x *= scale; vv.y *= scale; vv.z *= scale; vv.w *= scale;
    *(float4*)&xs[l >> 6][l & 63] = vv;
  }
  __syncthreads();

  float acc[4][16];
  #pragma unroll
  for (int r = 0; r < 4; r++)
    #pragma unroll
    for (int c = 0; c < 16; c++) acc[r][c] = 0.f;
  float nrm[4] = {0.f, 0.f, 0.f, 0.f};

  for (int d4 = 0; d4 < 64; d4 += 4) {
    float4 a[4];
    #pragma unroll
    for (int r = 0; r < 4; r++) {
      a[r] = *(float4*)&xs[r * 16 + ti][d4];
      nrm[r] += a[r].x * a[r].x + a[r].y * a[r].y + a[r].z * a[r].z + a[r].w * a[r].w;
    }
    #pragma unroll
    for (int c = 0; c < 16; c++) {
      float4 b = *(float4*)&wsm[c * 16 + tj][d4];
      #pragma unroll
      for (int r = 0; r < 4; r++)
        acc[r][c] += a[r].x * b.x + a[r].y * b.y + a[r].z * b.z + a[r].w * b.w;
    }
  }

  float gmax_k = 0.f;
  if (MODE == 2) gmax_k = dec_f(*kmax);

  float lp[4][16];
  float bmax = -3.4e38f;
  #pragma unroll
  for (int r = 0; r < 4; r++) {
    float hn = 0.5f * nrm[r];
    float rowm = -3.4e38f;
    #pragma unroll
    for (int c = 0; c < 16; c++) {
      lp[r][c] = acc[r][c] - hn;
      rowm = fmaxf(rowm, lp[r][c]);
    }
    rowm = fmaxf(rowm, __shfl_xor(rowm, 1, 64));
    rowm = fmaxf(rowm, __shfl_xor(rowm, 2, 64));
    rowm = fmaxf(rowm, __shfl_xor(rowm, 4, 64));
    rowm = fmaxf(rowm, __shfl_xor(rowm, 8, 64));
    if (MODE == 0) {
      #pragma unroll
      for (int c = 0; c < 16; c++)
        lp[r][c] = __expf(lp[r][c] - rowm) * 0.0625f + 1e-4f;
    } else if (MODE == 1) {
      bmax = fmaxf(bmax, rowm);
    } else {
      #pragma unroll
      for (int c = 0; c < 16; c++)
        lp[r][c] = __expf(lp[r][c] - gmax_k) * 0.0625f + 1e-4f;
    }
  }

  if (MODE == 1) {
    bmax = fmaxf(bmax, __shfl_xor(bmax, 16, 64));
    bmax = fmaxf(bmax, __shfl_xor(bmax, 32, 64));
    if ((tid & 63) == 0) redbuf[tid >> 6] = bmax;
    __syncthreads();
    if (tid == 0) {
      float m0 = fmaxf(fmaxf(redbuf[0], redbuf[1]), fmaxf(redbuf[2], redbuf[3]));
      atomicMax(kmax, enc_f(m0));
    }
    return;
  }

  __syncthreads();               // done reading wsm -> reuse as staging
  float* st = &wsm[0][0];        // needs 64*257=16448 <= 256*68=17408 floats
  #pragma unroll
  for (int r = 0; r < 4; r++)
    #pragma unroll
    for (int c = 0; c < 16; c++)
      st[(r * 16 + ti) * 257 + (c * 16 + tj)] = lp[r][c];
  __syncthreads();
  for (int l = tid * 2; l < 16384; l += 512) {
    int row = l >> 8, m = l & 255;
    float v0 = st[row * 257 + m], v1 = st[row * 257 + m + 1];
    *(uint_t*)(phiOut + (rowbase + row) * 256 + m) = pack2h(v0, v1);
  }
}

// ---------- per-chunk partial state: S_c[m][d] = sum_i phiK[i][m]*v[i][d]; z_c[m]
__global__ __launch_bounds__(256) void k_chunksum(
    const _Float16* __restrict__ phiK, const float* __restrict__ v,
    float* __restrict__ sp, float* __restrict__ zp)
{
  __shared__ float vs[128][68];
  const int tid = threadIdx.x;
  const int m = tid & 127;
  const int dof = (tid >> 7) * 32;
  const size_t nbase = (size_t)(blockIdx.x >> 5) * NSEQ + (size_t)(blockIdx.x & 31) * CHUNK;

  for (int l = tid * 4; l < 8192; l += 1024)
    *(float4*)&vs[l >> 6][l & 63] = *(const float4*)(v + nbase * 64 + l);
  __syncthreads();

  float s0[32], s1[32];
  #pragma unroll
  for (int d = 0; d < 32; d++) { s0[d] = 0.f; s1[d] = 0.f; }
  float z0 = 0.f, z1 = 0.f;
  const _Float16* pk = phiK + nbase * 256;
  for (int i = 0; i < CHUNK; i++) {
    float p0 = (float)pk[i * 256 + m];
    float p1 = (float)pk[i * 256 + 128 + m];
    z0 += p0; z1 += p1;
    #pragma unroll
    for (int d4 = 0; d4 < 32; d4 += 4) {
      float4 vv = *(float4*)&vs[i][dof + d4];
      s0[d4 + 0] += p0 * vv.x; s0[d4 + 1] += p0 * vv.y;
      s0[d4 + 2] += p0 * vv.z; s0[d4 + 3] += p0 * vv.w;
      s1[d4 + 0] += p1 * vv.x; s1[d4 + 1] += p1 * vv.y;
      s1[d4 + 2] += p1 * vv.z; s1[d4 + 3] += p1 * vv.w;
    }
  }
  float* so0 = sp + ((size_t)blockIdx.x * 256 + m) * 64 + dof;
  float* so1 = sp + ((size_t)blockIdx.x * 256 + 128 + m) * 64 + dof;
  #pragma unroll
  for (int d4 = 0; d4 < 32; d4 += 4) {
    *(float4*)(so0 + d4) = make_float4(s0[d4], s0[d4 + 1], s0[d4 + 2], s0[d4 + 3]);
    *(float4*)(so1 + d4) = make_float4(s1[d4], s1[d4 + 1], s1[d4 + 2], s1[d4 + 3]);
  }
  if (dof == 0) {
    zp[(size_t)blockIdx.x * 256 + m] = z0;
    zp[(size_t)blockIdx.x * 256 + 128 + m] = z1;
  }
}

// ---------- exclusive prefix over chunks (in place)
__global__ __launch_bounds__(256) void k_prefix(float* __restrict__ sp) {
  int idx = blockIdx.x * 256 + threadIdx.x;   // 0 .. BH*M*D-1
  int bh = idx >> 14;
  int r = idx & 16383;
  float* base = sp + (size_t)bh * (NCH * 16384) + r;
  float run = 0.f;
  for (int c = 0; c < NCH; c++) {
    float val = base[(size_t)c * 16384];
    base[(size_t)c * 16384] = run;
    run += val;
  }
}
__global__ __launch_bounds__(256) void k_prefixz(float* __restrict__ zp) {
  int idx = blockIdx.x * 256 + threadIdx.x;   // 0 .. BH*M-1
  int bh = idx >> 8;
  int r = idx & 255;
  float* base = zp + (size_t)bh * (NCH * 256) + r;
  float run = 0.f;
  for (int c = 0; c < NCH; c++) {
    float val = base[c * 256];
    base[c * 256] = run;
    run += val;
  }
}

// ---------- inter-chunk: out = phiQ @ S_prev ; den = phiQ . z_prev + 1e-6
__global__ __launch_bounds__(256) void k_inter(
    const _Float16* __restrict__ phiQ, const float* __restrict__ sp,
    const float* __restrict__ zp, float* __restrict__ out, float* __restrict__ den)
{
  __shared__ float qs[128][68];
  __shared__ float ss[64][68];
  __shared__ float zs[64];
  const int tid = threadIdx.x;
  const int ti = tid >> 4, tj = tid & 15;
  const size_t nbase = (size_t)(blockIdx.x >> 5) * NSEQ + (size_t)(blockIdx.x & 31) * CHUNK;

  float acc[8][4], accz[8];
  #pragma unroll
  for (int r = 0; r < 8; r++) {
    accz[r] = 0.f;
    acc[r][0] = acc[r][1] = acc[r][2] = acc[r][3] = 0.f;
  }

  for (int mt = 0; mt < 4; mt++) {
    for (int l = tid * 2; l < 8192; l += 512) {
      int row = l >> 6, mm = l & 63;
      uint_t u = *(const uint_t*)(phiQ + (nbase + row) * 256 + mt * 64 + mm);
      qs[row][mm] = h2f_lo(u); qs[row][mm + 1] = h2f_hi(u);
    }
    for (int l = tid * 4; l < 4096; l += 1024) {
      int mm = l >> 6, d = l & 63;
      *(float4*)&ss[mm][d] =
          *(const float4*)(sp + ((size_t)blockIdx.x * 256 + mt * 64 + mm) * 64 + d);
    }
    if (tid < 64) zs[tid] = zp[(size_t)blockIdx.x * 256 + mt * 64 + tid];
    __syncthreads();
    for (int mm = 0; mm < 64; mm += 4) {
      float4 aq[8];
      #pragma unroll
      for (int r = 0; r < 8; r++) aq[r] = *(float4*)&qs[r * 16 + ti][mm];
      #pragma unroll
      for (int t = 0; t < 4; t++) {
        float4 b = *(float4*)&ss[mm + t][tj * 4];
        float zv = zs[mm + t];
        #pragma unroll
        for (int r = 0; r < 8; r++) {
          float a = (t == 0) ? aq[r].x : (t == 1) ? aq[r].y : (t == 2) ? aq[r].z : aq[r].w;
          acc[r][0] += a * b.x; acc[r][1] += a * b.y;
          acc[r][2] += a * b.z; acc[r][3] += a * b.w;
          accz[r] += a * zv;
        }
      }
    }
    __syncthreads();
  }
  #pragma unroll
  for (int r = 0; r < 8; r++) {
    int i = r * 16 + ti;
    *(float4*)(out + (nbase + i) * 64 + tj * 4) =
        make_float4(acc[r][0], acc[r][1], acc[r][2], acc[r][3]);
    if (tj == 0) den[nbase + i] = accz[r] + 1e-6f;
  }
}

// ---------- intra-chunk: A = tril(phiQ @ phiK^T); out = (out + A@v) / (den + rowsum(A))
__global__ __launch_bounds__(256) void k_intra(
    const _Float16* __restrict__ phiQ, const _Float16* __restrict__ phiK,
    const float* __restrict__ v, float* __restrict__ out,
    const float* __restrict__ den)
{
  __shared__ float qs[128][68];    // phiQ tile; reused for v in phase C
  __shared__ float ks[128][68];
  __shared__ float As[128][132];
  __shared__ float dens[128];

  const int tid = threadIdx.x;
  const int ti = tid >> 4, tj = tid & 15;
  const size_t nbase = (size_t)(blockIdx.x >> 5) * NSEQ + (size_t)(blockIdx.x & 31) * CHUNK;

  float A[8][8];
  #pragma unroll
  for (int r = 0; r < 8; r++)
    #pragma unroll
    for (int c = 0; c < 8; c++) A[r][c] = 0.f;

  for (int mt = 0; mt < 4; mt++) {
    for (int l = tid * 2; l < 8192; l += 512) {
      int row = l >> 6, mm = l & 63;
      uint_t uq = *(const uint_t*)(phiQ + (nbase + row) * 256 + mt * 64 + mm);
      uint_t uk = *(const uint_t*)(phiK + (nbase + row) * 256 + mt * 64 + mm);
      qs[row][mm] = h2f_lo(uq); qs[row][mm + 1] = h2f_hi(uq);
      ks[row][mm] = h2f_lo(uk); ks[row][mm + 1] = h2f_hi(uk);
    }
    __syncthreads();
    for (int mm = 0; mm < 64; mm += 4) {
      float4 aq[8], bk[8];
      #pragma unroll
      for (int r = 0; r < 8; r++) aq[r] = *(float4*)&qs[r * 16 + ti][mm];
      #pragma unroll
      for (int c = 0; c < 8; c++) bk[c] = *(float4*)&ks[c * 16 + tj][mm];
      #pragma unroll
      for (int r = 0; r < 8; r++)
        #pragma unroll
        for (int c = 0; c < 8; c++)
          A[r][c] += aq[r].x * bk[c].x + aq[r].y * bk[c].y
                   + aq[r].z * bk[c].z + aq[r].w * bk[c].w;
    }
    __syncthreads();
  }

  #pragma unroll
  for (int r = 0; r < 8; r++) {
    int i = r * 16 + ti;
    float rs = 0.f;
    #pragma unroll
    for (int c = 0; c < 8; c++) {
      int j = c * 16 + tj;
      float val = (j <= i) ? A[r][c] : 0.f;
      As[i][j] = val;
      rs += val;
    }
    rs += __shfl_xor(rs, 1, 64);
    rs += __shfl_xor(rs, 2, 64);
    rs += __shfl_xor(rs, 4, 64);
    rs += __shfl_xor(rs, 8, 64);
    if (tj == 0) dens[i] = den[nbase + i] + rs;
  }
  for (int l = tid * 4; l < 8192; l += 1024)
    *(float4*)&qs[l >> 6][l & 63] = *(const float4*)(v + nbase * 64 + l);
  __syncthreads();

  float o[8][4];
  #pragma unroll
  for (int r = 0; r < 8; r++) { o[r][0] = o[r][1] = o[r][2] = o[r][3] = 0.f; }
  for (int j = 0; j < 128; j += 4) {
    float4 av[8];
    #pragma unroll
    for (int r = 0; r < 8; r++) av[r] = *(float4*)&As[r * 16 + ti][j];
    #pragma unroll
    for (int t = 0; t < 4; t++) {
      float4 v4 = *(float4*)&qs[j + t][tj * 4];
      #pragma unroll
      for (int r = 0; r < 8; r++) {
        float a = (t == 0) ? av[r].x : (t == 1) ? av[r].y : (t == 2) ? av[r].z : av[r].w;
        o[r][0] += a * v4.x; o[r][1] += a * v4.y;
        o[r][2] += a * v4.z; o[r][3] += a * v4.w;
      }
    }
  }
  #pragma unroll
  for (int r = 0; r < 8; r++) {
    int i = r * 16 + ti;
    float4 t4 = *(const float4*)(out + (nbase + i) * 64 + tj * 4);
    float dinv = 1.0f / dens[i];
    float4 res;
    res.x = (t4.x + o[r][0]) * dinv;
    res.y = (t4.y + o[r][1]) * dinv;
    res.z = (t4.z + o[r][2]) * dinv;
    res.w = (t4.w + o[r][3]) * dinv;
    *(float4*)(out + (nbase + i) * 64 + tj * 4) = res;
  }
}

// ---------- launcher ----------
// ws layout (bytes):  phiQ fp16 [BH*N*M]   @ 0          (67,108,864)
//                     phiK fp16 [BH*N*M]   @ 67108864   (67,108,864)
//                     Spart f32 [BH*NC*M*D]@ 134217728  (67,108,864)
//                     zpart f32 [BH*NC*M]  @ 201326592  ( 1,048,576)
//                     den   f32 [BH*N]     @ 202375168  (   524,288)
//                     kmax  u32            @ 202899456
// total ~193.5 MB
extern "C" void kernel_launch(void* const* d_in, const int* in_sizes, int n_in,
                              void* d_out, int out_size, void* d_ws, size_t ws_size,
                              hipStream_t stream) {
  const float* q = (const float*)d_in[0];
  const float* k = (const float*)d_in[1];
  const float* v = (const float*)d_in[2];
  const float* omega = (const float*)d_in[3];
  float* out = (float*)d_out;
  char* ws = (char*)d_ws;

  _Float16* phiQ = (_Float16*)(ws + 0);
  _Float16* phiK = (_Float16*)(ws + 67108864);
  float* sp = (float*)(ws + 134217728);
  float* zp = (float*)(ws + 201326592);
  float* den = (float*)(ws + 202375168);
  uint_t* kmax = (uint_t*)(ws + 202899456);

  k_init<<<1, 1, 0, stream>>>(kmax);
  k_proj<1><<<2048, 256, 0, stream>>>(k, omega, nullptr, kmax);
  k_proj<0><<<2048, 256, 0, stream>>>(q, omega, phiQ, kmax);
  k_proj<2><<<2048, 256, 0, stream>>>(k, omega, phiK, kmax);
  k_chunksum<<<1024, 256, 0, stream>>>(phiK, v, sp, zp);
  k_prefix<<<2048, 256, 0, stream>>>(sp);
  k_prefixz<<<32, 256, 0, stream>>>(zp);
  k_inter<<<1024, 256, 0, stream>>>(phiQ, sp, zp, out, den);
  k_intra<<<1024, 256, 0, stream>>>(phiQ, phiK, v, out, den);
}

// Round 2
// 226.236 us; speedup vs baseline: 4.1018x; 4.1018x over previous
//
#include <hip/hip_runtime.h>
#include <cstddef>

// B=2,H=16 -> BH=32
#define BH    32
#define NSEQ  4096
#define MFEAT 256
#define CHUNK 128
#define NCH   32
#define SROW  65          // 64 d-rows + 1 z-row
#define SPITCH (SROW*256) // 16640 floats per (bh,chunk) state

typedef unsigned int uint_t;
typedef _Float16 half_t;
typedef __attribute__((ext_vector_type(8))) _Float16 half8;
typedef __attribute__((ext_vector_type(4))) float f32x4;

__device__ __forceinline__ f32x4 mfma16(half8 a, half8 b, f32x4 c) {
  return __builtin_amdgcn_mfma_f32_16x16x32_f16(a, b, c, 0, 0, 0);
}

// order-preserving float<->uint for atomicMax on floats
__device__ __forceinline__ uint_t enc_f(float x) {
  uint_t u = __float_as_uint(x);
  return (u & 0x80000000u) ? ~u : (u | 0x80000000u);
}
__device__ __forceinline__ float dec_f(uint_t u) {
  u = (u & 0x80000000u) ? (u ^ 0x80000000u) : ~u;
  return __uint_as_float(u);
}

__global__ void k_init(uint_t* kmax) { *kmax = enc_f(-__builtin_inff()); }

// ============================================================================
// k_proj: proj[i][m] = sum_d (x[i][d]*s) * omega[m][d]  via MFMA
// MODE 0: phi_q (per-row max), MODE 1: global-k-max only, MODE 2: phi_k (gmax)
// Block: 64 rows, 4 waves; wave w owns rows [16w,16w+16), all 256 cols.
// A-frag: row=lane&15 (+16w), k=(lane>>4)*8+e  (K-contiguous b128)
// B-frag: col=lane&15 (+16ct), same k          (omega native [m][d] layout)
// C-frag: col=lane&15, row=(lane>>4)*4+r
// ============================================================================
template <int MODE>
__global__ __launch_bounds__(256, 2) void k_proj(
    const float* __restrict__ x, const float* __restrict__ omega,
    half_t* __restrict__ phiOut, uint_t* __restrict__ kmax)
{
  __shared__ half_t Wl[256][72];   // omega f16 [m][d]; reused as store staging
  __shared__ half_t xs[64][72];    // x*scale f16 [row][d]
  __shared__ float nrm[64];
  __shared__ float red[4];

  const int tid = threadIdx.x;
  const int lane = tid & 63;
  const int w = tid >> 6;
  const int lc = lane & 15, rg = lane >> 4;
  const size_t rowbase = (size_t)blockIdx.x * 64;
  const float scale = 0.35355339059327373f;  // 64^-0.25

  float gm = 0.f;
  if (MODE == 2) gm = dec_f(*kmax);

  // stage omega fp32 -> f16 LDS (L2-resident, 64KB)
  for (int l = tid; l < 4096; l += 256) {
    int m = l >> 4, d4 = (l & 15) * 4;
    float4 o = *(const float4*)(omega + m * 64 + d4);
    union { half_t h[4]; uint2 u; } cv;
    cv.h[0] = (half_t)o.x; cv.h[1] = (half_t)o.y;
    cv.h[2] = (half_t)o.z; cv.h[3] = (half_t)o.w;
    *(uint2*)&Wl[m][d4] = cv.u;
  }
  // stage x*scale -> f16; row norms in fp32 (exact-ish)
  {
    int r = tid >> 2, qd = tid & 3;   // 4 threads per row, 16 floats each
    float pn = 0.f;
    #pragma unroll
    for (int c = 0; c < 4; c++) {
      float4 xv = *(const float4*)(x + (rowbase + r) * 64 + qd * 16 + c * 4);
      xv.x *= scale; xv.y *= scale; xv.z *= scale; xv.w *= scale;
      pn += xv.x * xv.x + xv.y * xv.y + xv.z * xv.z + xv.w * xv.w;
      union { half_t h[4]; uint2 u; } cv;
      cv.h[0] = (half_t)xv.x; cv.h[1] = (half_t)xv.y;
      cv.h[2] = (half_t)xv.z; cv.h[3] = (half_t)xv.w;
      *(uint2*)&xs[r][qd * 16 + c * 4] = cv.u;
    }
    pn += __shfl_xor(pn, 1, 64);
    pn += __shfl_xor(pn, 2, 64);
    if ((tid & 3) == 0) nrm[r] = 0.5f * pn;
  }
  __syncthreads();

  f32x4 acc[16];
  #pragma unroll
  for (int ct = 0; ct < 16; ct++) acc[ct] = (f32x4){0.f, 0.f, 0.f, 0.f};

  const int koff = rg * 8;
  #pragma unroll
  for (int ks = 0; ks < 64; ks += 32) {
    half8 a = *(const half8*)&xs[w * 16 + lc][ks + koff];
    #pragma unroll
    for (int ct = 0; ct < 16; ct++) {
      half8 b = *(const half8*)&Wl[ct * 16 + lc][ks + koff];
      acc[ct] = mfma16(a, b, acc[ct]);
    }
  }

  float hn[4];
  #pragma unroll
  for (int r = 0; r < 4; r++) hn[r] = nrm[w * 16 + rg * 4 + r];

  if (MODE == 1) {
    float bm = -3.4e38f;
    #pragma unroll
    for (int ct = 0; ct < 16; ct++)
      #pragma unroll
      for (int r = 0; r < 4; r++) bm = fmaxf(bm, acc[ct][r] - hn[r]);
    #pragma unroll
    for (int off = 1; off < 64; off <<= 1) bm = fmaxf(bm, __shfl_xor(bm, off, 64));
    if (lane == 0) red[w] = bm;
    __syncthreads();
    if (tid == 0)
      atomicMax(kmax, enc_f(fmaxf(fmaxf(red[0], red[1]), fmaxf(red[2], red[3]))));
    return;
  }

  float phi[16][4];
  if (MODE == 0) {
    float rowm[4];
    #pragma unroll
    for (int r = 0; r < 4; r++) {
      float m0 = -3.4e38f;
      #pragma unroll
      for (int ct = 0; ct < 16; ct++) m0 = fmaxf(m0, acc[ct][r] - hn[r]);
      m0 = fmaxf(m0, __shfl_xor(m0, 1, 64));
      m0 = fmaxf(m0, __shfl_xor(m0, 2, 64));
      m0 = fmaxf(m0, __shfl_xor(m0, 4, 64));
      m0 = fmaxf(m0, __shfl_xor(m0, 8, 64));
      rowm[r] = m0;
    }
    #pragma unroll
    for (int ct = 0; ct < 16; ct++)
      #pragma unroll
      for (int r = 0; r < 4; r++)
        phi[ct][r] = __expf(acc[ct][r] - hn[r] - rowm[r]) * 0.0625f + 1e-4f;
  } else {  // MODE 2
    #pragma unroll
    for (int ct = 0; ct < 16; ct++)
      #pragma unroll
      for (int r = 0; r < 4; r++)
        phi[ct][r] = __expf(acc[ct][r] - hn[r] - gm) * 0.0625f + 1e-4f;
  }

  // stage to LDS (reuse Wl, stride 264 f16 = 528B, 16B-aligned), then vector store
  __syncthreads();
  half_t* st = &Wl[0][0];   // need 64*264 = 16896 <= 256*72 = 18432 f16
  #pragma unroll
  for (int ct = 0; ct < 16; ct++)
    #pragma unroll
    for (int r = 0; r < 4; r++)
      st[(w * 16 + rg * 4 + r) * 264 + ct * 16 + lc] = (half_t)phi[ct][r];
  __syncthreads();
  for (int l = tid; l < 2048; l += 256) {
    int row = l >> 5, c = (l & 31) * 8;
    half8 vv = *(const half8*)&st[row * 264 + c];
    *(half8*)(phiOut + (rowbase + row) * 256 + c) = vv;
  }
}

// ============================================================================
// k_chunksum: ST_c[d'][m] = sum_j vt[d'][j] * phiK[j][m], d' in [0,65)
//   (row 64 = z via ones-row in vt). Output fp32 [65][256] per (bh,chunk).
// A = vt[d'][j] (v transposed in LDS), B = pkT[m][j] (phiK transposed in LDS).
// m split in 2 halves of 128 to fit LDS. 2 blocks/CU.
// ============================================================================
__global__ __launch_bounds__(256, 2) void k_chunksum(
    const half_t* __restrict__ phiK, const float* __restrict__ v,
    float* __restrict__ sp)
{
  __shared__ half_t pkT[128][136];   // [m_local][j]
  __shared__ half_t vt[80][136];     // [d'][j], row64=ones, 65..79=0

  const int tid = threadIdx.x;
  const int lane = tid & 63;
  const int w = tid >> 6;
  const int lc = lane & 15, rg = lane >> 4, koff = rg * 8;
  const int bh = blockIdx.x >> 5, ch = blockIdx.x & 31;
  const size_t nbase = (size_t)bh * NSEQ + (size_t)ch * CHUNK;
  float* spb = sp + (size_t)blockIdx.x * SPITCH;

  // stage v^T (fp32 -> f16 transpose), ones row, zero rows
  for (int l = tid; l < 2048; l += 256) {
    int j = l >> 4, dq = (l & 15) * 4;
    float4 vv = *(const float4*)(v + (nbase + j) * 64 + dq);
    vt[dq + 0][j] = (half_t)vv.x; vt[dq + 1][j] = (half_t)vv.y;
    vt[dq + 2][j] = (half_t)vv.z; vt[dq + 3][j] = (half_t)vv.w;
  }
  if (tid < 128) vt[64][tid] = (half_t)1.0f;
  for (int l = tid; l < 1920; l += 256) vt[65 + (l >> 7)][l & 127] = (half_t)0.0f;

  for (int h = 0; h < 2; h++) {
    __syncthreads();   // protect pkT (and vt on first iter)
    for (int l = tid; l < 2048; l += 256) {
      int j = l >> 4, mc = (l & 15) * 8;
      half8 pk8 = *(const half8*)(phiK + (nbase + j) * 256 + h * 128 + mc);
      #pragma unroll
      for (int e = 0; e < 8; e++) pkT[mc + e][j] = pk8[e];
    }
    __syncthreads();

    f32x4 acc[5][2];
    #pragma unroll
    for (int rt = 0; rt < 5; rt++) {
      acc[rt][0] = (f32x4){0.f, 0.f, 0.f, 0.f};
      acc[rt][1] = (f32x4){0.f, 0.f, 0.f, 0.f};
    }
    #pragma unroll
    for (int ks = 0; ks < 128; ks += 32) {
      half8 b0 = *(const half8*)&pkT[(w * 2 + 0) * 16 + lc][ks + koff];
      half8 b1 = *(const half8*)&pkT[(w * 2 + 1) * 16 + lc][ks + koff];
      #pragma unroll
      for (int rt = 0; rt < 5; rt++) {
        half8 a = *(const half8*)&vt[rt * 16 + lc][ks + koff];
        acc[rt][0] = mfma16(a, b0, acc[rt][0]);
        acc[rt][1] = mfma16(a, b1, acc[rt][1]);
      }
    }
    #pragma unroll
    for (int rt = 0; rt < 5; rt++)
      #pragma unroll
      for (int c2 = 0; c2 < 2; c2++) {
        int m = h * 128 + (w * 2 + c2) * 16 + lc;
        #pragma unroll
        for (int r = 0; r < 4; r++) {
          int row = rt * 16 + rg * 4 + r;
          if (row < SROW) spb[row * 256 + m] = acc[rt][c2][r];
        }
      }
  }
}

// ============================================================================
// k_prefix: exclusive prefix-sum of S-states over the 32 chunks (in place)
// ============================================================================
__global__ __launch_bounds__(256) void k_prefix(float* __restrict__ sp) {
  int idx = blockIdx.x * 256 + threadIdx.x;   // < 32*16640
  int bh = idx / SPITCH;
  int r = idx - bh * SPITCH;
  float* base = sp + (size_t)bh * (NCH * SPITCH) + r;
  float run = 0.f;
  #pragma unroll 4
  for (int c = 0; c < NCH; c++) {
    float val = base[(size_t)c * SPITCH];
    base[(size_t)c * SPITCH] = run;
    run += val;
  }
}

// ============================================================================
// k_attn (fused inter+intra):
//   accA = phiQ @ phiK^T     [128x128], accO = phiQ @ Stilde^T [128x80]
//   mask accA causally -> f16 -> accO += Atilde @ vt_aug  [128x80]
//   out = accO[:, :64] / (accO[:, 64] + 1e-6)
// 4 waves; wave w owns q-rows [32w, 32w+32). 65.3 KB LDS -> 2 blocks/CU.
// ============================================================================
__global__ __launch_bounds__(256, 2) void k_attn(
    const half_t* __restrict__ phiQ, const half_t* __restrict__ phiK,
    const float* __restrict__ v, const float* __restrict__ sp,
    float* __restrict__ out)
{
  __shared__ half_t smemA[2 * 128 * 72];  // qs | ks ; aliased as vt[80][136]
  __shared__ half_t Ss[80][72];           // Stilde^T slice [n][m_local]
  __shared__ half_t As[128][72];          // masked A f16, one 64-col half

  half_t (*qs)[72]  = (half_t(*)[72])smemA;
  half_t (*ksl)[72] = (half_t(*)[72])(smemA + 128 * 72);
  half_t (*vt)[136] = (half_t(*)[136])smemA;

  const int tid = threadIdx.x;
  const int lane = tid & 63;
  const int w = tid >> 6;
  const int lc = lane & 15, rg = lane >> 4, koff = rg * 8;
  const int wr = w * 32;
  const int bh = blockIdx.x >> 5, ch = blockIdx.x & 31;
  const size_t nbase = (size_t)bh * NSEQ + (size_t)ch * CHUNK;
  const float* spb = sp + (size_t)blockIdx.x * SPITCH;

  // zero Ss pad rows once (cols 65..79 feed only unused accO cols)
  for (int l = tid; l < 15 * 72; l += 256) Ss[65 + l / 72][l % 72] = (half_t)0.0f;

  f32x4 accA[2][8], accO[2][5];
  #pragma unroll
  for (int rt = 0; rt < 2; rt++) {
    #pragma unroll
    for (int ct = 0; ct < 8; ct++) accA[rt][ct] = (f32x4){0.f, 0.f, 0.f, 0.f};
    #pragma unroll
    for (int cs = 0; cs < 5; cs++) accO[rt][cs] = (f32x4){0.f, 0.f, 0.f, 0.f};
  }

  // ---- phase 1: accumulate QK^T and Q@Stilde over 4 m-tiles of 64 ----
  for (int mt = 0; mt < 4; mt++) {
    __syncthreads();
    for (int l = tid; l < 1024; l += 256) {
      int row = l >> 3, c = (l & 7) * 8;
      *(half8*)&qs[row][c]  = *(const half8*)(phiQ + (nbase + row) * 256 + mt * 64 + c);
      *(half8*)&ksl[row][c] = *(const half8*)(phiK + (nbase + row) * 256 + mt * 64 + c);
    }
    for (int l = tid; l < 520; l += 256) {   // 65 rows x 8 chunks
      int n = l >> 3, c = (l & 7) * 8;
      const float* srcp = spb + n * 256 + mt * 64 + c;
      float4 a0 = *(const float4*)srcp;
      float4 a1 = *(const float4*)(srcp + 4);
      half8 hv;
      hv[0] = (half_t)a0.x; hv[1] = (half_t)a0.y; hv[2] = (half_t)a0.z; hv[3] = (half_t)a0.w;
      hv[4] = (half_t)a1.x; hv[5] = (half_t)a1.y; hv[6] = (half_t)a1.z; hv[7] = (half_t)a1.w;
      *(half8*)&Ss[n][c] = hv;
    }
    __syncthreads();
    #pragma unroll
    for (int ks2 = 0; ks2 < 64; ks2 += 32) {
      half8 a0 = *(const half8*)&qs[wr + lc][ks2 + koff];
      half8 a1 = *(const half8*)&qs[wr + 16 + lc][ks2 + koff];
      #pragma unroll
      for (int ct = 0; ct < 8; ct++) {
        half8 b = *(const half8*)&ksl[ct * 16 + lc][ks2 + koff];
        accA[0][ct] = mfma16(a0, b, accA[0][ct]);
        accA[1][ct] = mfma16(a1, b, accA[1][ct]);
      }
      #pragma unroll
      for (int cs = 0; cs < 5; cs++) {
        half8 b = *(const half8*)&Ss[cs * 16 + lc][ks2 + koff];
        accO[0][cs] = mfma16(a0, b, accO[0][cs]);
        accO[1][cs] = mfma16(a1, b, accO[1][cs]);
      }
    }
  }

  // ---- phase 2: vt staging (aliases qs/ks) + masked A @ v_aug ----
  __syncthreads();
  for (int l = tid; l < 2048; l += 256) {
    int j = l >> 4, dq = (l & 15) * 4;
    float4 vv = *(const float4*)(v + (nbase + j) * 64 + dq);
    vt[dq + 0][j] = (half_t)vv.x; vt[dq + 1][j] = (half_t)vv.y;
    vt[dq + 2][j] = (half_t)vv.z; vt[dq + 3][j] = (half_t)vv.w;
  }
  if (tid < 128) vt[64][tid] = (half_t)1.0f;
  for (int l = tid; l < 1920; l += 256) vt[65 + (l >> 7)][l & 127] = (half_t)0.0f;

  #pragma unroll
  for (int h = 0; h < 2; h++) {
    // stage this wave's masked-A half (wave-private rows -> no barrier needed
    // between halves; barrier below only for vt visibility on h==0)
    #pragma unroll
    for (int rt = 0; rt < 2; rt++)
      #pragma unroll
      for (int c4 = 0; c4 < 4; c4++) {
        int ct = h * 4 + c4;
        int j = ct * 16 + lc;
        #pragma unroll
        for (int r = 0; r < 4; r++) {
          int i = wr + rt * 16 + rg * 4 + r;
          float val = (j <= i) ? accA[rt][ct][r] : 0.f;
          As[i][j - h * 64] = (half_t)val;
        }
      }
    if (h == 0) __syncthreads();   // vt staged by all threads
    #pragma unroll
    for (int ks2 = 0; ks2 < 64; ks2 += 32) {
      half8 a0 = *(const half8*)&As[wr + lc][ks2 + koff];
      half8 a1 = *(const half8*)&As[wr + 16 + lc][ks2 + koff];
      #pragma unroll
      for (int cs = 0; cs < 5; cs++) {
        half8 b = *(const half8*)&vt[cs * 16 + lc][h * 64 + ks2 + koff];
        accO[0][cs] = mfma16(a0, b, accO[0][cs]);
        accO[1][cs] = mfma16(a1, b, accO[1][cs]);
      }
    }
  }

  // ---- epilogue: divide by den (col 64 of accO, held at lc==0 lanes) ----
  #pragma unroll
  for (int rt = 0; rt < 2; rt++)
    #pragma unroll
    for (int r = 0; r < 4; r++) {
      float den = __shfl(accO[rt][4][r], (lane & 48), 64) + 1e-6f;
      float inv = 1.0f / den;
      int i = wr + rt * 16 + rg * 4 + r;
      #pragma unroll
      for (int cs = 0; cs < 4; cs++)
        out[(nbase + i) * 64 + cs * 16 + lc] = accO[rt][cs][r] * inv;
    }
}

// ============================================================================
// launcher
// ws: phiQ f16 @0 (64MB) | phiK f16 @64MB | sp f32 @128MB (65*256*1024*4 =
//     68.16MB) | kmax u32 @202,375,168   -> ~202.4 MB total
// ============================================================================
extern "C" void kernel_launch(void* const* d_in, const int* in_sizes, int n_in,
                              void* d_out, int out_size, void* d_ws, size_t ws_size,
                              hipStream_t stream) {
  const float* q = (const float*)d_in[0];
  const float* k = (const float*)d_in[1];
  const float* v = (const float*)d_in[2];
  const float* omega = (const float*)d_in[3];
  float* out = (float*)d_out;
  char* ws = (char*)d_ws;

  half_t* phiQ = (half_t*)(ws + 0);
  half_t* phiK = (half_t*)(ws + 67108864);
  float*  sp   = (float*)(ws + 134217728);
  uint_t* kmax = (uint_t*)(ws + 202375168);

  k_init<<<1, 1, 0, stream>>>(kmax);
  k_proj<1><<<2048, 256, 0, stream>>>(k, omega, nullptr, kmax);
  k_proj<0><<<2048, 256, 0, stream>>>(q, omega, phiQ, kmax);
  k_proj<2><<<2048, 256, 0, stream>>>(k, omega, phiK, kmax);
  k_chunksum<<<1024, 256, 0, stream>>>(phiK, v, sp);
  k_prefix<<<2080, 256, 0, stream>>>(sp);
  k_attn<<<1024, 256, 0, stream>>>(phiQ, phiK, v, sp, out);
}

// Round 3
// 157.373 us; speedup vs baseline: 5.8967x; 1.4376x over previous
//
#include <hip/hip_runtime.h>
#include <cstddef>

// B=2,H=16 -> BH=32
#define BH    32
#define NSEQ  4096
#define MFEAT 256
#define CHUNK 128
#define NCH   32
#define SROW  65          // 64 d-rows + 1 z-row
#define SPITCH (SROW*256) // 16640 f16 per (bh,chunk) state

#define SCALE 0.35355339059327373f  // 64^-0.25

typedef unsigned int uint_t;
typedef _Float16 half_t;
typedef __attribute__((ext_vector_type(8))) _Float16 half8;
typedef __attribute__((ext_vector_type(4))) float f32x4;

__device__ __forceinline__ f32x4 mfma16(half8 a, half8 b, f32x4 c) {
  return __builtin_amdgcn_mfma_f32_16x16x32_f16(a, b, c, 0, 0, 0);
}
__device__ __forceinline__ uint_t enc_f(float x) {
  uint_t u = __float_as_uint(x);
  return (u & 0x80000000u) ? ~u : (u | 0x80000000u);
}
__device__ __forceinline__ float dec_f(uint_t u) {
  u = (u & 0x80000000u) ? (u ^ 0x80000000u) : ~u;
  return __uint_as_float(u);
}
__device__ __forceinline__ half8 cvt_h8(float4 a, float4 b) {
  half8 h;
  h[0] = (half_t)a.x; h[1] = (half_t)a.y; h[2] = (half_t)a.z; h[3] = (half_t)a.w;
  h[4] = (half_t)b.x; h[5] = (half_t)b.y; h[6] = (half_t)b.z; h[7] = (half_t)b.w;
  return h;
}

__global__ void k_init(uint_t* kmax) { *kmax = enc_f(-__builtin_inff()); }

// ============================================================================
// k_maxes: per block, 64 rows of q AND 64 rows of k.
//   q: rowmQ[row] = max_m (q_s @ w^T)   (norm cancels in per-row max)
//   k: atomicMax(kmax, max(proj - 0.5|x|^2)) over block
// ============================================================================
__global__ __launch_bounds__(256, 2) void k_maxes(
    const float* __restrict__ q, const float* __restrict__ kx,
    const float* __restrict__ omega, float* __restrict__ rowmQ,
    uint_t* __restrict__ kmax)
{
  __shared__ half_t Wl[256 * 72];
  __shared__ half_t xs[64 * 72];
  __shared__ float nrm[64];
  __shared__ float red[4];

  const int tid = threadIdx.x;
  const int lane = tid & 63;
  const int w = tid >> 6;
  const int lc = lane & 15, rg = lane >> 4, koff = rg * 8;
  const size_t rowbase = (size_t)blockIdx.x * 64;

  // omega fp32 -> f16 LDS
  for (int l = tid; l < 4096; l += 256) {
    int m = l >> 4, d4 = (l & 15) * 4;
    float4 o = *(const float4*)(omega + m * 64 + d4);
    half_t* p = &Wl[m * 72 + d4];
    p[0] = (half_t)o.x; p[1] = (half_t)o.y; p[2] = (half_t)o.z; p[3] = (half_t)o.w;
  }
  // stage q*scale
  {
    int r = tid >> 2, qd = tid & 3;
    #pragma unroll
    for (int c = 0; c < 4; c++) {
      float4 xv = *(const float4*)(q + (rowbase + r) * 64 + qd * 16 + c * 4);
      half_t* p = &xs[r * 72 + qd * 16 + c * 4];
      p[0] = (half_t)(xv.x * SCALE); p[1] = (half_t)(xv.y * SCALE);
      p[2] = (half_t)(xv.z * SCALE); p[3] = (half_t)(xv.w * SCALE);
    }
  }
  __syncthreads();
  // proj q -> per-row max
  {
    f32x4 acc[16];
    #pragma unroll
    for (int ct = 0; ct < 16; ct++) acc[ct] = (f32x4){0.f, 0.f, 0.f, 0.f};
    #pragma unroll
    for (int ks = 0; ks < 2; ks++) {
      half8 a = *(const half8*)&xs[(w * 16 + lc) * 72 + ks * 32 + koff];
      #pragma unroll
      for (int ct = 0; ct < 16; ct++) {
        half8 b = *(const half8*)&Wl[(ct * 16 + lc) * 72 + ks * 32 + koff];
        acc[ct] = mfma16(a, b, acc[ct]);
      }
    }
    #pragma unroll
    for (int r = 0; r < 4; r++) {
      float m0 = -3.4e38f;
      #pragma unroll
      for (int ct = 0; ct < 16; ct++) m0 = fmaxf(m0, acc[ct][r]);
      m0 = fmaxf(m0, __shfl_xor(m0, 1, 64));
      m0 = fmaxf(m0, __shfl_xor(m0, 2, 64));
      m0 = fmaxf(m0, __shfl_xor(m0, 4, 64));
      m0 = fmaxf(m0, __shfl_xor(m0, 8, 64));
      if (lc == 0) rowmQ[rowbase + w * 16 + rg * 4 + r] = m0;
    }
  }
  __syncthreads();
  // stage k*scale + norms
  {
    int r = tid >> 2, qd = tid & 3;
    float pn = 0.f;
    #pragma unroll
    for (int c = 0; c < 4; c++) {
      float4 xv = *(const float4*)(kx + (rowbase + r) * 64 + qd * 16 + c * 4);
      xv.x *= SCALE; xv.y *= SCALE; xv.z *= SCALE; xv.w *= SCALE;
      pn += xv.x * xv.x + xv.y * xv.y + xv.z * xv.z + xv.w * xv.w;
      half_t* p = &xs[r * 72 + qd * 16 + c * 4];
      p[0] = (half_t)xv.x; p[1] = (half_t)xv.y; p[2] = (half_t)xv.z; p[3] = (half_t)xv.w;
    }
    pn += __shfl_xor(pn, 1, 64);
    pn += __shfl_xor(pn, 2, 64);
    if ((tid & 3) == 0) nrm[r] = 0.5f * pn;
  }
  __syncthreads();
  // proj k -> global max
  {
    f32x4 acc[16];
    #pragma unroll
    for (int ct = 0; ct < 16; ct++) acc[ct] = (f32x4){0.f, 0.f, 0.f, 0.f};
    #pragma unroll
    for (int ks = 0; ks < 2; ks++) {
      half8 a = *(const half8*)&xs[(w * 16 + lc) * 72 + ks * 32 + koff];
      #pragma unroll
      for (int ct = 0; ct < 16; ct++) {
        half8 b = *(const half8*)&Wl[(ct * 16 + lc) * 72 + ks * 32 + koff];
        acc[ct] = mfma16(a, b, acc[ct]);
      }
    }
    float hn[4];
    #pragma unroll
    for (int r = 0; r < 4; r++) hn[r] = nrm[w * 16 + rg * 4 + r];
    float bm = -3.4e38f;
    #pragma unroll
    for (int ct = 0; ct < 16; ct++)
      #pragma unroll
      for (int r = 0; r < 4; r++) bm = fmaxf(bm, acc[ct][r] - hn[r]);
    #pragma unroll
    for (int off = 1; off < 64; off <<= 1) bm = fmaxf(bm, __shfl_xor(bm, off, 64));
    if (lane == 0) red[w] = bm;
    __syncthreads();
    if (tid == 0)
      atomicMax(kmax, enc_f(fmaxf(fmaxf(red[0], red[1]), fmaxf(red[2], red[3]))));
  }
}

// ============================================================================
// k_state: fused phi_k projection + chunk partial state.
//   spA[blk][d'][m] = sum_j v_aug[d'][j] * phiK[j][m]   (d'=64 is z-row), f16
// ============================================================================
__global__ __launch_bounds__(256, 2) void k_state(
    const float* __restrict__ kx, const float* __restrict__ v,
    const float* __restrict__ omega, const uint_t* __restrict__ kmax,
    half_t* __restrict__ spA)
{
  __shared__ half_t WP[256 * 72];   // omega; aliased by pkT[128][144] (same size)
  __shared__ half_t vt[80 * 136];   // [d'][j]; row64=ones; 65..79 garbage (unused)
  __shared__ float nrmK[128];

  const int tid = threadIdx.x;
  const int lane = tid & 63;
  const int w = tid >> 6;
  const int lc = lane & 15, rg = lane >> 4, koff = rg * 8;
  const int wr = w * 32;
  const int blk = blockIdx.x;
  const size_t nbase = (size_t)(blk >> 5) * NSEQ + (size_t)(blk & 31) * CHUNK;
  const float gmaxv = dec_f(*kmax);

  // omega -> f16 LDS
  for (int l = tid; l < 4096; l += 256) {
    int m = l >> 4, d4 = (l & 15) * 4;
    float4 o = *(const float4*)(omega + m * 64 + d4);
    half_t* p = &WP[m * 72 + d4];
    p[0] = (half_t)o.x; p[1] = (half_t)o.y; p[2] = (half_t)o.z; p[3] = (half_t)o.w;
  }
  // v^T -> f16 LDS + ones row
  for (int l = tid; l < 2048; l += 256) {
    int j = l >> 4, dq = (l & 15) * 4;
    float4 vv = *(const float4*)(v + (nbase + j) * 64 + dq);
    vt[(dq + 0) * 136 + j] = (half_t)vv.x;
    vt[(dq + 1) * 136 + j] = (half_t)vv.y;
    vt[(dq + 2) * 136 + j] = (half_t)vv.z;
    vt[(dq + 3) * 136 + j] = (half_t)vv.w;
  }
  if (tid < 128) vt[64 * 136 + tid] = (half_t)1.0f;

  // k a-frags (direct global->reg) + norms
  half8 ak[2][2];
  float pn[2] = {0.f, 0.f};
  #pragma unroll
  for (int rt = 0; rt < 2; rt++) {
    const float* kp = kx + (nbase + wr + rt * 16 + lc) * 64 + koff;
    #pragma unroll
    for (int ks = 0; ks < 2; ks++) {
      float4 a = *(const float4*)(kp + ks * 32);
      float4 b = *(const float4*)(kp + ks * 32 + 4);
      a.x *= SCALE; a.y *= SCALE; a.z *= SCALE; a.w *= SCALE;
      b.x *= SCALE; b.y *= SCALE; b.z *= SCALE; b.w *= SCALE;
      pn[rt] += a.x * a.x + a.y * a.y + a.z * a.z + a.w * a.w
              + b.x * b.x + b.y * b.y + b.z * b.z + b.w * b.w;
      ak[rt][ks] = cvt_h8(a, b);
    }
    pn[rt] += __shfl_xor(pn[rt], 16, 64);
    pn[rt] += __shfl_xor(pn[rt], 32, 64);
  }
  if (rg == 0) {
    nrmK[wr + lc] = 0.5f * pn[0];
    nrmK[wr + 16 + lc] = 0.5f * pn[1];
  }
  __syncthreads();

  // proj k over all 256 m
  f32x4 accP[2][16];
  #pragma unroll
  for (int rt = 0; rt < 2; rt++)
    #pragma unroll
    for (int ct = 0; ct < 16; ct++) accP[rt][ct] = (f32x4){0.f, 0.f, 0.f, 0.f};
  #pragma unroll
  for (int ks = 0; ks < 2; ks++)
    #pragma unroll
    for (int ct = 0; ct < 16; ct++) {
      half8 b = *(const half8*)&WP[(ct * 16 + lc) * 72 + ks * 32 + koff];
      accP[0][ct] = mfma16(ak[0][ks], b, accP[0][ct]);
      accP[1][ct] = mfma16(ak[1][ks], b, accP[1][ct]);
    }
  // phi_k
  float hnr[2][4];
  #pragma unroll
  for (int rt = 0; rt < 2; rt++)
    #pragma unroll
    for (int r = 0; r < 4; r++) hnr[rt][r] = nrmK[wr + rt * 16 + rg * 4 + r];
  #pragma unroll
  for (int rt = 0; rt < 2; rt++)
    #pragma unroll
    for (int ct = 0; ct < 16; ct++)
      #pragma unroll
      for (int r = 0; r < 4; r++)
        accP[rt][ct][r] = __expf(accP[rt][ct][r] - hnr[rt][r] - gmaxv) * 0.0625f + 1e-4f;

  // two m-halves: transpose phiK into pkT (aliases WP), then state MFMA
  half_t* pkT = WP;  // [128][144]
  #pragma unroll
  for (int h = 0; h < 2; h++) {
    __syncthreads();   // h=0: proj reads of WP done; h=1: MFMA reads of pkT done
    #pragma unroll
    for (int rt = 0; rt < 2; rt++)
      #pragma unroll
      for (int c8 = 0; c8 < 8; c8++) {
        int ct = h * 8 + c8;
        #pragma unroll
        for (int r = 0; r < 4; r++)
          pkT[(c8 * 16 + lc) * 144 + wr + rt * 16 + rg * 4 + r] = (half_t)accP[rt][ct][r];
      }
    __syncthreads();
    f32x4 acc2[5][2];
    #pragma unroll
    for (int rt = 0; rt < 5; rt++) {
      acc2[rt][0] = (f32x4){0.f, 0.f, 0.f, 0.f};
      acc2[rt][1] = (f32x4){0.f, 0.f, 0.f, 0.f};
    }
    #pragma unroll
    for (int ks = 0; ks < 4; ks++) {
      half8 b0 = *(const half8*)&pkT[((2 * w + 0) * 16 + lc) * 144 + ks * 32 + koff];
      half8 b1 = *(const half8*)&pkT[((2 * w + 1) * 16 + lc) * 144 + ks * 32 + koff];
      #pragma unroll
      for (int rt = 0; rt < 5; rt++) {
        half8 a = *(const half8*)&vt[(rt * 16 + lc) * 136 + ks * 32 + koff];
        acc2[rt][0] = mfma16(a, b0, acc2[rt][0]);
        acc2[rt][1] = mfma16(a, b1, acc2[rt][1]);
      }
    }
    #pragma unroll
    for (int rt = 0; rt < 5; rt++)
      #pragma unroll
      for (int c2 = 0; c2 < 2; c2++)
        #pragma unroll
        for (int r = 0; r < 4; r++) {
          int row = rt * 16 + rg * 4 + r;
          if (row < SROW)
            spA[(size_t)blk * SPITCH + row * 256 + h * 128 + (2 * w + c2) * 16 + lc] =
                (half_t)acc2[rt][c2][r];
        }
  }
}

// ============================================================================
// k_prefix: exclusive prefix over 32 chunks, f16 in (spA) -> f16 out (spB),
// fp32 accumulation. One thread = 2 f16 lanes (one uint).
// ============================================================================
__global__ __launch_bounds__(256) void k_prefix(
    const uint_t* __restrict__ spA, uint_t* __restrict__ spB)
{
  int r = blockIdx.x * 256 + threadIdx.x;   // uint index within state (8320)
  if (r >= SPITCH / 2) return;
  int bh = blockIdx.y;
  const uint_t* src = spA + (size_t)bh * NCH * (SPITCH / 2) + r;
  uint_t* dst = spB + (size_t)bh * NCH * (SPITCH / 2) + r;
  float r0 = 0.f, r1 = 0.f;
  for (int c = 0; c < NCH; c++) {
    union { uint_t u; half_t h[2]; } cv, ov;
    cv.u = src[(size_t)c * (SPITCH / 2)];
    ov.h[0] = (half_t)r0; ov.h[1] = (half_t)r1;
    dst[(size_t)c * (SPITCH / 2)] = ov.u;
    r0 += (float)cv.h[0];
    r1 += (float)cv.h[1];
  }
}

// ============================================================================
// k_attn2: fused phi_q/phi_k projection + QK^T + Q@Stilde + masked A@v + div.
// den comes free as output column 64 (z-row of Stilde + ones-row of v_aug).
// LDS 48.9 KB; per-mt: stage Sst + omega frags, proj->PQ/PK, accumulate.
// ============================================================================
__global__ __launch_bounds__(256, 2) void k_attn2(
    const float* __restrict__ q, const float* __restrict__ kx,
    const float* __restrict__ v, const float* __restrict__ omega,
    const float* __restrict__ rowmQ, const uint_t* __restrict__ kmax,
    const half_t* __restrict__ spB, float* __restrict__ out)
{
  __shared__ half_t sm[24192];   // PQ[128*72] | PK[128*72] | SST[80*72]
  __shared__ float nrmK[128];
  half_t* PQ  = sm;              // phase2: AS aliases this
  half_t* PK  = sm + 9216;       // phase2: VT starts here ([80][136])
  half_t* SST = sm + 18432;
  half_t* AS  = sm;
  half_t* VT  = sm + 9216;

  const int tid = threadIdx.x;
  const int lane = tid & 63;
  const int w = tid >> 6;
  const int lc = lane & 15, rg = lane >> 4, koff = rg * 8;
  const int wr = w * 32;
  const int blk = blockIdx.x;
  const size_t nbase = (size_t)(blk >> 5) * NSEQ + (size_t)(blk & 31) * CHUNK;
  const half_t* spb = spB + (size_t)blk * SPITCH;
  const float gmaxv = dec_f(*kmax);

  float rowm[2][4];
  #pragma unroll
  for (int rt = 0; rt < 2; rt++)
    #pragma unroll
    for (int r = 0; r < 4; r++)
      rowm[rt][r] = rowmQ[nbase + wr + rt * 16 + rg * 4 + r];

  // q,k a-frags direct global->reg (scaled), k norms
  half8 aq[2][2], ak[2][2];
  float pn[2] = {0.f, 0.f};
  #pragma unroll
  for (int rt = 0; rt < 2; rt++) {
    const float* qp = q + (nbase + wr + rt * 16 + lc) * 64 + koff;
    const float* kp = kx + (nbase + wr + rt * 16 + lc) * 64 + koff;
    #pragma unroll
    for (int ks = 0; ks < 2; ks++) {
      float4 a = *(const float4*)(qp + ks * 32);
      float4 b = *(const float4*)(qp + ks * 32 + 4);
      a.x *= SCALE; a.y *= SCALE; a.z *= SCALE; a.w *= SCALE;
      b.x *= SCALE; b.y *= SCALE; b.z *= SCALE; b.w *= SCALE;
      aq[rt][ks] = cvt_h8(a, b);
      float4 c = *(const float4*)(kp + ks * 32);
      float4 d = *(const float4*)(kp + ks * 32 + 4);
      c.x *= SCALE; c.y *= SCALE; c.z *= SCALE; c.w *= SCALE;
      d.x *= SCALE; d.y *= SCALE; d.z *= SCALE; d.w *= SCALE;
      pn[rt] += c.x * c.x + c.y * c.y + c.z * c.z + c.w * c.w
              + d.x * d.x + d.y * d.y + d.z * d.z + d.w * d.w;
      ak[rt][ks] = cvt_h8(c, d);
    }
    pn[rt] += __shfl_xor(pn[rt], 16, 64);
    pn[rt] += __shfl_xor(pn[rt], 32, 64);
  }
  if (rg == 0) {
    nrmK[wr + lc] = 0.5f * pn[0];
    nrmK[wr + 16 + lc] = 0.5f * pn[1];
  }
  __syncthreads();
  float hnr[2][4];
  #pragma unroll
  for (int rt = 0; rt < 2; rt++)
    #pragma unroll
    for (int r = 0; r < 4; r++) hnr[rt][r] = nrmK[wr + rt * 16 + rg * 4 + r];

  f32x4 accA[2][8], accO[2][5];
  #pragma unroll
  for (int rt = 0; rt < 2; rt++) {
    #pragma unroll
    for (int ct = 0; ct < 8; ct++) accA[rt][ct] = (f32x4){0.f, 0.f, 0.f, 0.f};
    #pragma unroll
    for (int cs = 0; cs < 5; cs++) accO[rt][cs] = (f32x4){0.f, 0.f, 0.f, 0.f};
  }

  // ---- phase 1: per 64-m tile: proj q/k -> PQ/PK; accumulate QK^T, Q@S ----
  for (int mt = 0; mt < 4; mt++) {
    __syncthreads();   // prev MFMA reads of PQ/PK/SST complete
    for (int l = tid; l < 520; l += 256) {
      int row = l >> 3, c8 = (l & 7) * 8;
      *(half8*)&SST[row * 72 + c8] = *(const half8*)(spb + row * 256 + mt * 64 + c8);
    }
    half8 bw[4][2];
    #pragma unroll
    for (int ct = 0; ct < 4; ct++) {
      const float* op = omega + (mt * 64 + ct * 16 + lc) * 64 + koff;
      #pragma unroll
      for (int ks = 0; ks < 2; ks++) {
        float4 a = *(const float4*)(op + ks * 32);
        float4 b = *(const float4*)(op + ks * 32 + 4);
        bw[ct][ks] = cvt_h8(a, b);
      }
    }
    // proj q
    f32x4 accP[2][4];
    #pragma unroll
    for (int rt = 0; rt < 2; rt++)
      #pragma unroll
      for (int ct = 0; ct < 4; ct++) accP[rt][ct] = (f32x4){0.f, 0.f, 0.f, 0.f};
    #pragma unroll
    for (int ks = 0; ks < 2; ks++)
      #pragma unroll
      for (int ct = 0; ct < 4; ct++) {
        accP[0][ct] = mfma16(aq[0][ks], bw[ct][ks], accP[0][ct]);
        accP[1][ct] = mfma16(aq[1][ks], bw[ct][ks], accP[1][ct]);
      }
    #pragma unroll
    for (int rt = 0; rt < 2; rt++)
      #pragma unroll
      for (int ct = 0; ct < 4; ct++)
        #pragma unroll
        for (int r = 0; r < 4; r++) {
          float val = __expf(accP[rt][ct][r] - rowm[rt][r]) * 0.0625f + 1e-4f;
          PQ[(wr + rt * 16 + rg * 4 + r) * 72 + ct * 16 + lc] = (half_t)val;
        }
    // proj k
    #pragma unroll
    for (int rt = 0; rt < 2; rt++)
      #pragma unroll
      for (int ct = 0; ct < 4; ct++) accP[rt][ct] = (f32x4){0.f, 0.f, 0.f, 0.f};
    #pragma unroll
    for (int ks = 0; ks < 2; ks++)
      #pragma unroll
      for (int ct = 0; ct < 4; ct++) {
        accP[0][ct] = mfma16(ak[0][ks], bw[ct][ks], accP[0][ct]);
        accP[1][ct] = mfma16(ak[1][ks], bw[ct][ks], accP[1][ct]);
      }
    #pragma unroll
    for (int rt = 0; rt < 2; rt++)
      #pragma unroll
      for (int ct = 0; ct < 4; ct++)
        #pragma unroll
        for (int r = 0; r < 4; r++) {
          float val = __expf(accP[rt][ct][r] - hnr[rt][r] - gmaxv) * 0.0625f + 1e-4f;
          PK[(wr + rt * 16 + rg * 4 + r) * 72 + ct * 16 + lc] = (half_t)val;
        }
    __syncthreads();
    #pragma unroll
    for (int ks2 = 0; ks2 < 64; ks2 += 32) {
      half8 a0 = *(const half8*)&PQ[(wr + lc) * 72 + ks2 + koff];
      half8 a1 = *(const half8*)&PQ[(wr + 16 + lc) * 72 + ks2 + koff];
      #pragma unroll
      for (int ct = 0; ct < 8; ct++) {
        half8 b = *(const half8*)&PK[(ct * 16 + lc) * 72 + ks2 + koff];
        accA[0][ct] = mfma16(a0, b, accA[0][ct]);
        accA[1][ct] = mfma16(a1, b, accA[1][ct]);
      }
      #pragma unroll
      for (int cs = 0; cs < 5; cs++) {
        half8 b = *(const half8*)&SST[(cs * 16 + lc) * 72 + ks2 + koff];
        accO[0][cs] = mfma16(a0, b, accO[0][cs]);
        accO[1][cs] = mfma16(a1, b, accO[1][cs]);
      }
    }
  }

  // ---- phase 2: masked A @ v_aug (ones row -> rowsum lands in col 64) ----
  __syncthreads();
  for (int l = tid; l < 2048; l += 256) {
    int j = l >> 4, dq = (l & 15) * 4;
    float4 vv = *(const float4*)(v + (nbase + j) * 64 + dq);
    VT[(dq + 0) * 136 + j] = (half_t)vv.x;
    VT[(dq + 1) * 136 + j] = (half_t)vv.y;
    VT[(dq + 2) * 136 + j] = (half_t)vv.z;
    VT[(dq + 3) * 136 + j] = (half_t)vv.w;
  }
  if (tid < 128) VT[64 * 136 + tid] = (half_t)1.0f;

  #pragma unroll
  for (int h = 0; h < 2; h++) {
    #pragma unroll
    for (int rt = 0; rt < 2; rt++)
      #pragma unroll
      for (int c4 = 0; c4 < 4; c4++) {
        int ct = h * 4 + c4;
        int j = ct * 16 + lc;
        #pragma unroll
        for (int r = 0; r < 4; r++) {
          int i = wr + rt * 16 + rg * 4 + r;
          float val = (j <= i) ? accA[rt][ct][r] : 0.f;
          AS[i * 72 + (j - h * 64)] = (half_t)val;
        }
      }
    if (h == 0) __syncthreads();   // VT staged by all threads
    #pragma unroll
    for (int ks2 = 0; ks2 < 64; ks2 += 32) {
      half8 a0 = *(const half8*)&AS[(wr + lc) * 72 + ks2 + koff];
      half8 a1 = *(const half8*)&AS[(wr + 16 + lc) * 72 + ks2 + koff];
      #pragma unroll
      for (int cs = 0; cs < 5; cs++) {
        half8 b = *(const half8*)&VT[(cs * 16 + lc) * 136 + h * 64 + ks2 + koff];
        accO[0][cs] = mfma16(a0, b, accO[0][cs]);
        accO[1][cs] = mfma16(a1, b, accO[1][cs]);
      }
    }
  }

  // ---- epilogue: divide by den (col 64 of accO) ----
  #pragma unroll
  for (int rt = 0; rt < 2; rt++)
    #pragma unroll
    for (int r = 0; r < 4; r++) {
      float den = __shfl(accO[rt][4][r], (lane & 48), 64) + 1e-6f;
      float inv = 1.0f / den;
      int i = wr + rt * 16 + rg * 4 + r;
      #pragma unroll
      for (int cs = 0; cs < 4; cs++)
        out[(nbase + i) * 64 + cs * 16 + lc] = accO[rt][cs][r] * inv;
    }
}

// ============================================================================
// launcher
// ws: rowmQ f32 @0 (512KB) | spA f16 @524288 (32.5MB) | spB f16 @34603008
//     (32.5MB) | kmax u32 @68681728   -> ~68.7 MB total
// ============================================================================
extern "C" void kernel_launch(void* const* d_in, const int* in_sizes, int n_in,
                              void* d_out, int out_size, void* d_ws, size_t ws_size,
                              hipStream_t stream) {
  const float* q = (const float*)d_in[0];
  const float* k = (const float*)d_in[1];
  const float* v = (const float*)d_in[2];
  const float* omega = (const float*)d_in[3];
  float* out = (float*)d_out;
  char* ws = (char*)d_ws;

  float*  rowmQ = (float*)(ws + 0);
  half_t* spA   = (half_t*)(ws + 524288);
  half_t* spB   = (half_t*)(ws + 34603008);
  uint_t* kmax  = (uint_t*)(ws + 68681728);

  k_init<<<1, 1, 0, stream>>>(kmax);
  k_maxes<<<2048, 256, 0, stream>>>(q, k, omega, rowmQ, kmax);
  k_state<<<1024, 256, 0, stream>>>(k, v, omega, kmax, spA);
  k_prefix<<<dim3(33, 32), 256, 0, stream>>>((const uint_t*)spA, (uint_t*)spB);
  k_attn2<<<1024, 256, 0, stream>>>(q, k, v, omega, rowmQ, kmax, spB, out);
}